// Round 1
// baseline (10211.702 us; speedup 1.0000x reference)
//
#include <hip/hip_runtime.h>

// LightGCN propagation on MI355X.
// N = 100000 nodes, D = 128, E = 2,000,000 edges, 3 layers.
// out = (x0 + x1 + x2 + x3) / 4 where x_{l+1}[r] = sum_e rows[e]==r vals[e]*x_l[cols[e]]
//
// Round 0 design: COO scatter with hardware fp32 atomics.
//   - ping-pong x buffers in d_ws (2 * N*D*4 = 102.4 MB)
//   - accumulator lives in d_out
//   - per edge: 32 threads, one float4 (4 dims) each -> coalesced 512B gather
//   - unsafeAtomicAdd => global_atomic_add_f32 (no CAS loop)

#define DIM 128
#define DIM4 32  // DIM / 4

__global__ void lgcn_init(const float4* __restrict__ emb,
                          float4* __restrict__ xcur,
                          float4* __restrict__ acc,
                          long n4) {
    long i = (long)blockIdx.x * blockDim.x + threadIdx.x;
    if (i < n4) {
        float4 v = emb[i];
        xcur[i] = v;
        acc[i] = v;
    }
}

__global__ void lgcn_zero(float4* __restrict__ p, long n4) {
    long i = (long)blockIdx.x * blockDim.x + threadIdx.x;
    if (i < n4) p[i] = make_float4(0.f, 0.f, 0.f, 0.f);
}

__global__ void lgcn_scatter(const int* __restrict__ rows,
                             const int* __restrict__ cols,
                             const float* __restrict__ vals,
                             const float4* __restrict__ xcur,
                             float* __restrict__ xnext,
                             int nedges) {
    long t = (long)blockIdx.x * blockDim.x + threadIdx.x;
    int e  = (int)(t >> 5);   // edge index
    int d4 = (int)(t & 31);   // which float4 of the 128-dim row
    if (e >= nedges) return;
    int   r = rows[e];
    int   c = cols[e];
    float v = vals[e];
    float4 x = xcur[(long)c * DIM4 + d4];
    float* dst = xnext + (long)r * DIM + d4 * 4;
    unsafeAtomicAdd(dst + 0, v * x.x);
    unsafeAtomicAdd(dst + 1, v * x.y);
    unsafeAtomicAdd(dst + 2, v * x.z);
    unsafeAtomicAdd(dst + 3, v * x.w);
}

__global__ void lgcn_acc(float4* __restrict__ acc,
                         const float4* __restrict__ xnext,
                         long n4) {
    long i = (long)blockIdx.x * blockDim.x + threadIdx.x;
    if (i < n4) {
        float4 a = acc[i];
        float4 b = xnext[i];
        a.x += b.x; a.y += b.y; a.z += b.z; a.w += b.w;
        acc[i] = a;
    }
}

__global__ void lgcn_scale(float4* __restrict__ acc, long n4, float s) {
    long i = (long)blockIdx.x * blockDim.x + threadIdx.x;
    if (i < n4) {
        float4 a = acc[i];
        a.x *= s; a.y *= s; a.z *= s; a.w *= s;
        acc[i] = a;
    }
}

extern "C" void kernel_launch(void* const* d_in, const int* in_sizes, int n_in,
                              void* d_out, int out_size, void* d_ws, size_t ws_size,
                              hipStream_t stream) {
    const float* emb  = (const float*)d_in[0];
    const int*   rows = (const int*)d_in[1];
    const int*   cols = (const int*)d_in[2];
    const float* vals = (const float*)d_in[3];

    const long n_nodes = in_sizes[0] / DIM;   // 100000
    const int  nedges  = in_sizes[1];         // 2000000
    const long nd      = n_nodes * DIM;       // 12.8M floats
    const long n4      = nd / 4;              // 3.2M float4

    float* xcur  = (float*)d_ws;
    float* xnext = (float*)d_ws + nd;
    float* acc   = (float*)d_out;

    const int BS = 256;
    const int grid_n4 = (int)((n4 + BS - 1) / BS);
    const long scatter_threads = (long)nedges * DIM4;
    const int grid_sc = (int)((scatter_threads + BS - 1) / BS);

    // acc = emb; xcur = emb
    lgcn_init<<<grid_n4, BS, 0, stream>>>((const float4*)emb, (float4*)xcur,
                                          (float4*)acc, n4);

    for (int layer = 0; layer < 3; ++layer) {
        lgcn_zero<<<grid_n4, BS, 0, stream>>>((float4*)xnext, n4);
        lgcn_scatter<<<grid_sc, BS, 0, stream>>>(rows, cols, vals,
                                                 (const float4*)xcur, xnext, nedges);
        lgcn_acc<<<grid_n4, BS, 0, stream>>>((float4*)acc, (const float4*)xnext, n4);
        float* tmp = xcur; xcur = xnext; xnext = tmp;
    }

    lgcn_scale<<<grid_n4, BS, 0, stream>>>((float4*)acc, n4, 0.25f);
}

// Round 2
// 840.181 us; speedup vs baseline: 12.1542x; 12.1542x over previous
//
#include <hip/hip_runtime.h>

// LightGCN propagation on MI355X — round 2: gather-side CSR SpMM.
// N = 100000 nodes, D = 128, E = 2,000,000 edges, 3 layers.
//
// Round-1 scatter was atomic-write-amplification bound (WRITE_SIZE 4 GB per
// layer for 1 GB of payload). Round 2 builds CSR on-device every call
// (histogram -> scan -> fill; graph-capture-safe, same work each call), then
// each layer is one gather SpMM: one wave per row, one write per output row,
// zero atomics in the inner loop.
//
// ws layout (floats/ints), nd = N*128:
//   xA        : nd floats
//   xB        : nd floats
//   row_ptr   : N+1 ints
//   cursor    : N ints  (fill cursors, copy of exclusive scan)
//   counts    : N ints  (degree histogram)
//   col_s     : E ints  (CSR column indices)
//   val_s     : E floats(CSR values)

#define DIM 128

__global__ void lgcn_hist(const int* __restrict__ rows, int* __restrict__ counts,
                          int nedges) {
    int e = blockIdx.x * blockDim.x + threadIdx.x;
    if (e < nedges) atomicAdd(&counts[rows[e]], 1);
}

// Single-block exclusive scan of counts[0..n) -> row_ptr[0..n], cursor[0..n).
// 1024 threads, wave-shuffle scan + 16-wave LDS combine.
__global__ void __launch_bounds__(1024)
lgcn_scan(const int* __restrict__ counts, int* __restrict__ row_ptr,
          int* __restrict__ cursor, int n) {
    __shared__ int wsum[16];
    const int tid  = threadIdx.x;
    const int lane = tid & 63;
    const int wid  = tid >> 6;
    int base = 0;
    for (int chunk = 0; chunk < n; chunk += 1024) {
        int i = chunk + tid;
        int c = (i < n) ? counts[i] : 0;
        // wave inclusive scan
        int incl = c;
        #pragma unroll
        for (int off = 1; off < 64; off <<= 1) {
            int t = __shfl_up(incl, off, 64);
            if (lane >= off) incl += t;
        }
        if (lane == 63) wsum[wid] = incl;
        __syncthreads();
        if (wid == 0 && lane < 16) {
            int w = wsum[lane];
            #pragma unroll
            for (int off = 1; off < 16; off <<= 1) {
                int t = __shfl_up(w, off, 64);
                if (lane >= off) w += t;
            }
            wsum[lane] = w;
        }
        __syncthreads();
        int waveoff = (wid > 0) ? wsum[wid - 1] : 0;
        int total   = wsum[15];
        if (i < n) {
            int ex = base + waveoff + incl - c;
            row_ptr[i] = ex;
            cursor[i]  = ex;
        }
        base += total;
        __syncthreads();  // protect wsum before next chunk overwrites it
    }
    if (tid == 0) row_ptr[n] = base;
}

__global__ void lgcn_fill(const int* __restrict__ rows, const int* __restrict__ cols,
                          const float* __restrict__ vals, int* __restrict__ cursor,
                          int* __restrict__ col_s, float* __restrict__ val_s,
                          int nedges) {
    int e = blockIdx.x * blockDim.x + threadIdx.x;
    if (e < nedges) {
        int r   = rows[e];
        int pos = atomicAdd(&cursor[r], 1);
        col_s[pos] = cols[e];
        val_s[pos] = vals[e];
    }
}

// One wave (64 lanes) per row; lane j holds dims [2j, 2j+1] as float2.
// mode 0: xout = s;           acc = xin[row] + s        (layer 1, acc init)
// mode 1: xout = s;           acc += s                  (layer 2)
// mode 2: (no xout)           acc = (acc + s) * 0.25    (layer 3 + finalize)
__global__ void __launch_bounds__(256)
lgcn_spmm(const int* __restrict__ row_ptr, const int* __restrict__ col_s,
          const float* __restrict__ val_s, const float2* __restrict__ xin,
          float2* __restrict__ xout, float2* __restrict__ acc,
          int n, int mode) {
    const int wave = blockIdx.x * (blockDim.x >> 6) + (threadIdx.x >> 6);
    const int lane = threadIdx.x & 63;
    if (wave >= n) return;
    const int r   = wave;
    const int beg = row_ptr[r];
    const int end = row_ptr[r + 1];

    float sx = 0.f, sy = 0.f;
    int e = beg;
    for (; e + 4 <= end; e += 4) {
        int   c0 = col_s[e + 0], c1 = col_s[e + 1];
        int   c2 = col_s[e + 2], c3 = col_s[e + 3];
        float v0 = val_s[e + 0], v1 = val_s[e + 1];
        float v2 = val_s[e + 2], v3 = val_s[e + 3];
        float2 a0 = xin[(long)c0 * 64 + lane];
        float2 a1 = xin[(long)c1 * 64 + lane];
        float2 a2 = xin[(long)c2 * 64 + lane];
        float2 a3 = xin[(long)c3 * 64 + lane];
        sx += v0 * a0.x; sy += v0 * a0.y;
        sx += v1 * a1.x; sy += v1 * a1.y;
        sx += v2 * a2.x; sy += v2 * a2.y;
        sx += v3 * a3.x; sy += v3 * a3.y;
    }
    for (; e < end; ++e) {
        int   c = col_s[e];
        float v = val_s[e];
        float2 a = xin[(long)c * 64 + lane];
        sx += v * a.x; sy += v * a.y;
    }

    const long o = (long)r * 64 + lane;
    if (mode == 0) {
        xout[o] = make_float2(sx, sy);
        float2 em = xin[o];
        acc[o] = make_float2(em.x + sx, em.y + sy);
    } else if (mode == 1) {
        xout[o] = make_float2(sx, sy);
        float2 a = acc[o];
        acc[o] = make_float2(a.x + sx, a.y + sy);
    } else {
        float2 a = acc[o];
        acc[o] = make_float2((a.x + sx) * 0.25f, (a.y + sy) * 0.25f);
    }
}

extern "C" void kernel_launch(void* const* d_in, const int* in_sizes, int n_in,
                              void* d_out, int out_size, void* d_ws, size_t ws_size,
                              hipStream_t stream) {
    const float* emb  = (const float*)d_in[0];
    const int*   rows = (const int*)d_in[1];
    const int*   cols = (const int*)d_in[2];
    const float* vals = (const float*)d_in[3];

    const int  n_nodes = in_sizes[0] / DIM;   // 100000
    const int  nedges  = in_sizes[1];         // 2000000
    const long nd      = (long)n_nodes * DIM; // 12.8M floats

    char* ws = (char*)d_ws;
    float* xA      = (float*)ws;                 ws += nd * sizeof(float);
    float* xB      = (float*)ws;                 ws += nd * sizeof(float);
    int*   row_ptr = (int*)ws;                   ws += (long)(n_nodes + 1) * sizeof(int);
    int*   cursor  = (int*)ws;                   ws += (long)n_nodes * sizeof(int);
    int*   counts  = (int*)ws;                   ws += (long)n_nodes * sizeof(int);
    int*   col_s   = (int*)ws;                   ws += (long)nedges * sizeof(int);
    float* val_s   = (float*)ws;                 ws += (long)nedges * sizeof(float);
    float* acc     = (float*)d_out;

    const int BS = 256;
    const int grid_e = (nedges + BS - 1) / BS;

    // --- CSR build (every call; graph-capture safe) ---
    hipMemsetAsync(counts, 0, (size_t)n_nodes * sizeof(int), stream);
    lgcn_hist<<<grid_e, BS, 0, stream>>>(rows, counts, nedges);
    lgcn_scan<<<1, 1024, 0, stream>>>(counts, row_ptr, cursor, n_nodes);
    lgcn_fill<<<grid_e, BS, 0, stream>>>(rows, cols, vals, cursor, col_s, val_s, nedges);

    // --- 3 SpMM layers, acc fused ---
    const int grid_s = (n_nodes + 3) / 4;  // 4 waves (rows) per 256-thread block
    lgcn_spmm<<<grid_s, BS, 0, stream>>>(row_ptr, col_s, val_s,
                                         (const float2*)emb, (float2*)xA,
                                         (float2*)acc, n_nodes, 0);
    lgcn_spmm<<<grid_s, BS, 0, stream>>>(row_ptr, col_s, val_s,
                                         (const float2*)xA, (float2*)xB,
                                         (float2*)acc, n_nodes, 1);
    lgcn_spmm<<<grid_s, BS, 0, stream>>>(row_ptr, col_s, val_s,
                                         (const float2*)xB, (float2*)nullptr,
                                         (float2*)acc, n_nodes, 2);
}

// Round 3
// 592.774 us; speedup vs baseline: 17.2270x; 1.4174x over previous
//
#include <hip/hip_runtime.h>
#include <hip/hip_fp16.h>

// LightGCN propagation on MI355X — round 3: fp16 gather + parallel CSR build.
// N = 100000 nodes, D = 128, E = 2,000,000 edges, 3 layers.
//
// Round-2 was gather-traffic bound (501 MB HBM fetch per SpMM for 1.07 GB
// logical gathers) plus ~366 us of CSR-build overhead (serial single-block
// scan). Round 3:
//   - x stored as fp16 (values <=0.5, fp16 rel err 2^-11 -> safe vs 2.6e-3
//     threshold): gather bytes halve (256 B/row).
//   - no fp32 acc RMW chain: layers 1-2 just store x_l; layer 3 fuses
//     out = (emb + x1 + x2 + x3) * 0.25 with coalesced reads.
//   - two-level parallel scan (3 light kernels) instead of single-block scan.
//   - edges packed as int2 (col, val bits): one 8 B scattered store in fill,
//     one 8 B broadcast load per edge in spmm.
//
// ws layout (256 B aligned slices):
//   bufA : nd fp16 (x0, later reused for x2)     25.6 MB
//   bufB : nd fp16 (x1)                           25.6 MB
//   edges: E int2                                 16 MB
//   counts, row_ptr(+1), cursor, bsums            ~1.2 MB

#define DIM 128

static inline size_t align_up(size_t v, size_t a) { return (v + a - 1) & ~(a - 1); }

__global__ void lgcn_conv(const float2* __restrict__ emb, __half2* __restrict__ x0,
                          int n2) {
    int i = blockIdx.x * blockDim.x + threadIdx.x;
    if (i < n2) x0[i] = __float22half2_rn(emb[i]);
}

__global__ void lgcn_hist(const int* __restrict__ rows, int* __restrict__ counts,
                          int nedges) {
    int e = blockIdx.x * blockDim.x + threadIdx.x;
    if (e < nedges) atomicAdd(&counts[rows[e]], 1);
}

// Level-1 scan: each 256-thread block scans 1024 counts (4/thread).
// Writes per-element block-local exclusive prefix into row_ptr[i],
// block total into bsums[blk].
__global__ void __launch_bounds__(256)
lgcn_scan1(const int* __restrict__ counts, int* __restrict__ row_ptr,
           int* __restrict__ bsums, int n) {
    __shared__ int wsum[4];
    const int tid  = threadIdx.x;
    const int lane = tid & 63;
    const int wid  = tid >> 6;
    const int i0   = blockIdx.x * 1024 + tid * 4;

    int c0 = 0, c1 = 0, c2 = 0, c3 = 0;
    if (i0 + 3 < n) {
        int4 c = *(const int4*)(counts + i0);
        c0 = c.x; c1 = c.y; c2 = c.z; c3 = c.w;
    } else {
        if (i0 + 0 < n) c0 = counts[i0 + 0];
        if (i0 + 1 < n) c1 = counts[i0 + 1];
        if (i0 + 2 < n) c2 = counts[i0 + 2];
        if (i0 + 3 < n) c3 = counts[i0 + 3];
    }
    const int t1 = c0 + c1, t2 = t1 + c2, tsum = t2 + c3;

    // wave inclusive scan of per-thread sums
    int incl = tsum;
    #pragma unroll
    for (int off = 1; off < 64; off <<= 1) {
        int t = __shfl_up(incl, off, 64);
        if (lane >= off) incl += t;
    }
    if (lane == 63) wsum[wid] = incl;
    __syncthreads();
    int woff = 0;
    #pragma unroll
    for (int w = 0; w < 4; ++w) woff += (w < wid) ? wsum[w] : 0;

    const int ex = woff + incl - tsum;  // exclusive prefix of this thread's chunk
    if (i0 + 0 < n) row_ptr[i0 + 0] = ex;
    if (i0 + 1 < n) row_ptr[i0 + 1] = ex + c0;
    if (i0 + 2 < n) row_ptr[i0 + 2] = ex + t1;
    if (i0 + 3 < n) row_ptr[i0 + 3] = ex + t2;
    if (tid == 255) bsums[blockIdx.x] = woff + incl;
}

// Level-2: exclusive-scan the (<=128) block sums in one block; write total.
__global__ void __launch_bounds__(128)
lgcn_scan2(int* __restrict__ bsums, int* __restrict__ row_ptr, int nb, int n) {
    __shared__ int w0s;
    const int tid  = threadIdx.x;
    const int lane = tid & 63;
    const int wid  = tid >> 6;
    int v = (tid < nb) ? bsums[tid] : 0;
    int incl = v;
    #pragma unroll
    for (int off = 1; off < 64; off <<= 1) {
        int t = __shfl_up(incl, off, 64);
        if (lane >= off) incl += t;
    }
    if (tid == 63) w0s = incl;
    __syncthreads();
    const int ex = incl - v + ((wid == 1) ? w0s : 0);
    if (tid < nb) bsums[tid] = ex;
    if (tid == nb - 1) row_ptr[n] = ex + v;
}

// Level-3: add block bases; produce final row_ptr and fill cursors.
__global__ void lgcn_scan3(int* __restrict__ row_ptr, int* __restrict__ cursor,
                           const int* __restrict__ bsums, int n) {
    int i = blockIdx.x * blockDim.x + threadIdx.x;
    if (i < n) {
        int v = row_ptr[i] + bsums[i >> 10];
        row_ptr[i] = v;
        cursor[i]  = v;
    }
}

__global__ void lgcn_fill(const int* __restrict__ rows, const int* __restrict__ cols,
                          const float* __restrict__ vals, int* __restrict__ cursor,
                          int2* __restrict__ edges, int nedges) {
    int e = blockIdx.x * blockDim.x + threadIdx.x;
    if (e < nedges) {
        int r   = rows[e];
        int pos = atomicAdd(&cursor[r], 1);
        edges[pos] = make_int2(cols[e], __float_as_int(vals[e]));
    }
}

// One wave per row; lane j holds dims [2j, 2j+1] (one __half2 = 4 B gather/lane).
// mode 0: xout[row] = fp16(s)
// mode 1: out[row]  = (emb[row] + x1[row] + xin[row](=x2) + s) * 0.25  (fp32)
__global__ void __launch_bounds__(256)
lgcn_spmm(const int* __restrict__ row_ptr, const int2* __restrict__ edges,
          const __half2* __restrict__ xin, __half2* __restrict__ xout,
          const float2* __restrict__ emb, const __half2* __restrict__ x1h,
          float2* __restrict__ out, int n, int mode) {
    const int wave = blockIdx.x * 4 + (threadIdx.x >> 6);
    const int lane = threadIdx.x & 63;
    if (wave >= n) return;
    const int beg = row_ptr[wave];
    const int end = row_ptr[wave + 1];

    float sx = 0.f, sy = 0.f;
    int e = beg;
    for (; e + 4 <= end; e += 4) {
        int2 p0 = edges[e + 0], p1 = edges[e + 1];
        int2 p2 = edges[e + 2], p3 = edges[e + 3];
        float2 a0 = __half22float2(xin[p0.x * 64 + lane]);
        float2 a1 = __half22float2(xin[p1.x * 64 + lane]);
        float2 a2 = __half22float2(xin[p2.x * 64 + lane]);
        float2 a3 = __half22float2(xin[p3.x * 64 + lane]);
        float v0 = __int_as_float(p0.y), v1 = __int_as_float(p1.y);
        float v2 = __int_as_float(p2.y), v3 = __int_as_float(p3.y);
        sx = fmaf(v0, a0.x, sx); sy = fmaf(v0, a0.y, sy);
        sx = fmaf(v1, a1.x, sx); sy = fmaf(v1, a1.y, sy);
        sx = fmaf(v2, a2.x, sx); sy = fmaf(v2, a2.y, sy);
        sx = fmaf(v3, a3.x, sx); sy = fmaf(v3, a3.y, sy);
    }
    for (; e < end; ++e) {
        int2 p = edges[e];
        float2 a = __half22float2(xin[p.x * 64 + lane]);
        float v  = __int_as_float(p.y);
        sx = fmaf(v, a.x, sx); sy = fmaf(v, a.y, sy);
    }

    const int o = wave * 64 + lane;
    if (mode == 0) {
        xout[o] = __float22half2_rn(make_float2(sx, sy));
    } else {
        float2 em = emb[o];
        float2 b1 = __half22float2(x1h[o]);
        float2 b2 = __half22float2(xin[o]);
        out[o] = make_float2((em.x + b1.x + b2.x + sx) * 0.25f,
                             (em.y + b1.y + b2.y + sy) * 0.25f);
    }
}

extern "C" void kernel_launch(void* const* d_in, const int* in_sizes, int n_in,
                              void* d_out, int out_size, void* d_ws, size_t ws_size,
                              hipStream_t stream) {
    const float* emb  = (const float*)d_in[0];
    const int*   rows = (const int*)d_in[1];
    const int*   cols = (const int*)d_in[2];
    const float* vals = (const float*)d_in[3];

    const int  n_nodes = in_sizes[0] / DIM;    // 100000
    const int  nedges  = in_sizes[1];          // 2000000
    const long nd      = (long)n_nodes * DIM;  // 12.8M

    char* ws = (char*)d_ws;
    size_t off = 0;
    __half2* bufA = (__half2*)(ws + off); off = align_up(off + nd * 2, 256);   // x0 then x2
    __half2* bufB = (__half2*)(ws + off); off = align_up(off + nd * 2, 256);   // x1
    int2* edges   = (int2*)(ws + off);    off = align_up(off + (size_t)nedges * 8, 256);
    int* counts   = (int*)(ws + off);     off = align_up(off + (size_t)n_nodes * 4, 256);
    int* row_ptr  = (int*)(ws + off);     off = align_up(off + (size_t)(n_nodes + 1) * 4, 256);
    int* cursor   = (int*)(ws + off);     off = align_up(off + (size_t)n_nodes * 4, 256);
    int* bsums    = (int*)(ws + off);     off = align_up(off + 1024, 256);
    float2* out   = (float2*)d_out;

    const int BS = 256;
    const int grid_e  = (nedges + BS - 1) / BS;
    const int n2      = (int)(nd / 2);
    const int grid_c  = (n2 + BS - 1) / BS;
    const int nb      = (n_nodes + 1023) / 1024;          // 98 (<=128)
    const int grid_n  = (n_nodes + BS - 1) / BS;
    const int grid_s  = (n_nodes + 3) / 4;                // 4 rows per block

    // emb -> fp16 x0
    lgcn_conv<<<grid_c, BS, 0, stream>>>((const float2*)emb, bufA, n2);

    // CSR build
    hipMemsetAsync(counts, 0, (size_t)n_nodes * sizeof(int), stream);
    lgcn_hist<<<grid_e, BS, 0, stream>>>(rows, counts, nedges);
    lgcn_scan1<<<nb, 256, 0, stream>>>(counts, row_ptr, bsums, n_nodes);
    lgcn_scan2<<<1, 128, 0, stream>>>(bsums, row_ptr, nb, n_nodes);
    lgcn_scan3<<<grid_n, BS, 0, stream>>>(row_ptr, cursor, bsums, n_nodes);
    lgcn_fill<<<grid_e, BS, 0, stream>>>(rows, cols, vals, cursor, edges, nedges);

    // 3 SpMM layers: x1 = A x0, x2 = A x1, out = (emb + x1 + x2 + A x2)/4
    lgcn_spmm<<<grid_s, BS, 0, stream>>>(row_ptr, edges, bufA, bufB,
                                         nullptr, nullptr, nullptr, n_nodes, 0);
    lgcn_spmm<<<grid_s, BS, 0, stream>>>(row_ptr, edges, bufB, bufA,
                                         nullptr, nullptr, nullptr, n_nodes, 0);
    lgcn_spmm<<<grid_s, BS, 0, stream>>>(row_ptr, edges, bufA, nullptr,
                                         (const float2*)emb, bufB, out, n_nodes, 1);
}